// Round 11
// baseline (241.280 us; speedup 1.0000x reference)
//
#include <hip/hip_runtime.h>

// Problem constants (fixed by the reference)
#define VOCAB 50000
#define D     300
#define B_    64
#define LC    32
#define T_    256
#define LT    64
#define NSEL  5
#define NCAND 16              // noisy-candidate buffer for exact rescoring

// A-image geometry: 32 rows x 40 slots (16B = 8 f16), k padded 300->320,
// slot s stored at s ^ (m&7) -> conflict-free ds_read_b128.
// hi: uint4[0..1280), lo: uint4[1280..2560). 40960 B per batch.
#define A_U4   2560
#define A_HALF 20480
#define TROW   320            // hi-ONLY table row: 320 halfs = 640 B = 10 lines

typedef _Float16 half8_t __attribute__((ext_vector_type(8)));
typedef float    f32x4   __attribute__((ext_vector_type(4)));

// Session ledger:
//  R1 depth-3 / R3 8-waves-per-EU: register spill walls. 16 waves/CU @ 128.
//  R2: setprio +4% cost (lockstep waves, T5 null) — out.
//  R5: 3x MLP -> BW pinned ~3.3 TB/s, FETCH 2x. SERVE-RATE LAW:
//      dur = FETCH / ~3.3 TB/s in every config. Bytes are the only lever.
//  R7: 64B fill granule. R8: f32 rows unaligned -> +19% bytes (alignment!).
//  R9: hi-only 640B selection rows + exact top-16 rescore: k_scores 103us,
//      FETCH 293MB (~1.24x per-XCD union), absmax exact. LLC random-64B
//      serve rate ~3.1 TB/s is the pin.
//  R10: parallel rescore tail: 266->235us. k_scores unchanged.
//  R11 (this): k_prep was 13,012 tiny blocks (~4.8KB work each) — suspected
//      dispatch-rate-bound (~65-100us). Grid-stride: 1627 blocks x 32 rows.
//      Bitwise-identical stores; absmax must stay 2^-10.

// ---------------- K0: merged prep: hi-only table + claim images --------------
// Table: block i in [0, tableBlocks) handles rows i*32 + it*4 + wave, it=0..7.
// Claims: block tableBlocks+j (j in [0,64)) handles rows j*32 + it*4 + wave.
__global__ __launch_bounds__(256) void k_prep(const int* __restrict__ claim,
                                              const float* __restrict__ emb,
                                              _Float16* __restrict__ tab,
                                              _Float16* __restrict__ wsA,
                                              int tableBlocks) {
    int wave = threadIdx.x >> 6, lane = threadIdx.x & 63;
    if ((int)blockIdx.x < tableBlocks) {
#pragma unroll
        for (int it = 0; it < 8; ++it) {
            int r = blockIdx.x * 32 + it * 4 + wave;     // 1563*32 >= 50000
            if (r < VOCAB) {
                const float* src = emb + (size_t)r * D;
                _Float16* d = tab + (size_t)r * TROW;
#pragma unroll
                for (int i = 0; i < 5; ++i) {
                    int k = lane + i * 64;
                    d[k] = (k < D) ? (_Float16)src[k] : (_Float16)0.0f;
                }
            }
        }
    } else {
#pragma unroll
        for (int it = 0; it < 8; ++it) {
            int row = (blockIdx.x - tableBlocks) * 32 + it * 4 + wave;  // 0..2047
            int b = row >> 5, m = row & 31;
            int tok = claim[row];
            const float* src = emb + (size_t)tok * D;
            _Float16* base = wsA + (size_t)b * A_HALF;
#pragma unroll
            for (int i = 0; i < 5; ++i) {
                int k = lane + i * 64;
                float x = (k < D) ? src[k] : 0.0f;
                _Float16 h = (_Float16)x;
                int sp = ((k >> 3) ^ (m & 7));
                int idx = (m * 40 + sp) * 8 + (k & 7);
                base[idx] = h;
                base[10240 + idx] = (_Float16)(x - (float)h);
            }
        }
    }
}

// hi/lo split of a float4 pair into half8 hi and half8 lo (exact path)
__device__ __forceinline__ void split8(const float4& a, const float4& b,
                                       half8_t& hv, half8_t& lv) {
    float x[8] = {a.x, a.y, a.z, a.w, b.x, b.y, b.z, b.w};
#pragma unroll
    for (int i = 0; i < 8; ++i) {
        _Float16 h = (_Float16)x[i];
        hv[i] = h;
        lv[i] = (_Float16)(x[i] - (float)h);
    }
}

// ---------------- exact K-loop (f32 emb gather + on-the-fly split) -----------
// Bitwise identical to R8's passing path: 3 MFMAs (ah*bh, ah*bl, al*bh).
template<int NI>
__device__ __forceinline__ void compute_exact(const uint4* sA,
                                              const float* __restrict__ emb,
                                              const int* __restrict__ trow, int lcol0,
                                              int lane, f32x4 acc[2][NI]) {
    int ln = lane & 15, quad = lane >> 4;
#pragma unroll
    for (int mi = 0; mi < 2; ++mi)
#pragma unroll
        for (int ni = 0; ni < NI; ++ni) acc[mi][ni] = (f32x4)0.0f;

    int arow0 = ln * 40;
    int arow1 = (16 + ln) * 40;
    int key = ln & 7;
    int qo = quad * 8;

    const float* bp[NI];
#pragma unroll
    for (int ni = 0; ni < NI; ++ni) {
        int tok = trow[lcol0 + ni * 16 + ln];
        bp[ni] = emb + (size_t)tok * D;
    }
#pragma unroll 1
    for (int ks = 0; ks < 10; ++ks) {
        int kb = ks * 32 + qo;
        int ka = kb > 296 ? 296 : kb;
        int kb4 = kb + 4;
        int kbb = kb4 > 296 ? 296 : kb4;
        float4 b0[NI], b1[NI];
#pragma unroll
        for (int ni = 0; ni < NI; ++ni) {
            b0[ni] = *(const float4*)(bp[ni] + ka);
            b1[ni] = *(const float4*)(bp[ni] + kbb);
        }
        if (kb >= 296) {
            float4 z = make_float4(0.f, 0.f, 0.f, 0.f);
#pragma unroll
            for (int ni = 0; ni < NI; ++ni) {
                if (kb >= 300) b0[ni] = z;
                b1[ni] = z;
            }
        }
        int sp = (ks * 4 + quad) ^ key;
        half8_t ah[2], al[2];
        ah[0] = __builtin_bit_cast(half8_t, sA[arow0 + sp]);
        al[0] = __builtin_bit_cast(half8_t, sA[1280 + arow0 + sp]);
        ah[1] = __builtin_bit_cast(half8_t, sA[arow1 + sp]);
        al[1] = __builtin_bit_cast(half8_t, sA[1280 + arow1 + sp]);
        half8_t bh[NI], bl[NI];
#pragma unroll
        for (int ni = 0; ni < NI; ++ni) split8(b0[ni], b1[ni], bh[ni], bl[ni]);
#pragma unroll
        for (int mi = 0; mi < 2; ++mi)
#pragma unroll
            for (int ni = 0; ni < NI; ++ni) {
                acc[mi][ni] = __builtin_amdgcn_mfma_f32_16x16x32_f16(ah[mi], bh[ni], acc[mi][ni], 0, 0, 0);
                acc[mi][ni] = __builtin_amdgcn_mfma_f32_16x16x32_f16(ah[mi], bl[ni], acc[mi][ni], 0, 0, 0);
                acc[mi][ni] = __builtin_amdgcn_mfma_f32_16x16x32_f16(al[mi], bh[ni], acc[mi][ni], 0, 0, 0);
            }
    }
}

// ---------------- noisy K-loop (hi-only 640B table rows, selection only) -----
__device__ __forceinline__ void compute_noisy(const uint4* sA,
                                              const _Float16* __restrict__ tab,
                                              const int* __restrict__ trow,
                                              int lane, f32x4 acc[2][4]) {
    int ln = lane & 15, quad = lane >> 4;
#pragma unroll
    for (int mi = 0; mi < 2; ++mi)
#pragma unroll
        for (int ni = 0; ni < 4; ++ni) acc[mi][ni] = (f32x4)0.0f;

    int arow0 = ln * 40;
    int arow1 = (16 + ln) * 40;
    int key = ln & 7;
    int qo = quad * 8;

    const _Float16* rp[4];
#pragma unroll
    for (int ni = 0; ni < 4; ++ni) {
        int tok = trow[ni * 16 + ln];
        rp[ni] = tab + (size_t)tok * TROW;
    }
    half8_t bh[2][4];
#pragma unroll
    for (int ni = 0; ni < 4; ++ni) bh[0][ni] = *(const half8_t*)(rp[ni] + qo);
#pragma unroll
    for (int ks = 0; ks < 10; ++ks) {
        int cur = ks & 1, nxt = cur ^ 1;
        if (ks < 9) {
            int ko = (ks + 1) * 32 + qo;
#pragma unroll
            for (int ni = 0; ni < 4; ++ni)
                bh[nxt][ni] = *(const half8_t*)(rp[ni] + ko);
        }
        int sp = (ks * 4 + quad) ^ key;
        half8_t ah[2], al[2];
        ah[0] = __builtin_bit_cast(half8_t, sA[arow0 + sp]);
        al[0] = __builtin_bit_cast(half8_t, sA[1280 + arow0 + sp]);
        ah[1] = __builtin_bit_cast(half8_t, sA[arow1 + sp]);
        al[1] = __builtin_bit_cast(half8_t, sA[1280 + arow1 + sp]);
#pragma unroll
        for (int mi = 0; mi < 2; ++mi)
#pragma unroll
            for (int ni = 0; ni < 4; ++ni) {
                acc[mi][ni] = __builtin_amdgcn_mfma_f32_16x16x32_f16(ah[mi], bh[cur][ni], acc[mi][ni], 0, 0, 0);
                acc[mi][ni] = __builtin_amdgcn_mfma_f32_16x16x32_f16(al[mi], bh[cur][ni], acc[mi][ni], 0, 0, 0);
            }
    }
}

__device__ __forceinline__ float xmax4(float v) {
    v = fmaxf(v, __shfl_xor(v, 1)); v = fmaxf(v, __shfl_xor(v, 2));
    v = fmaxf(v, __shfl_xor(v, 4)); v = fmaxf(v, __shfl_xor(v, 8));
    return v;
}
__device__ __forceinline__ float xsum4(float v) {
    v += __shfl_xor(v, 1); v += __shfl_xor(v, 2);
    v += __shfl_xor(v, 4); v += __shfl_xor(v, 8);
    return v;
}

// target score from a wave's acc[2][4] — op order identical to R0..R10.
__device__ __forceinline__ float score_from_acc(f32x4 acc[2][4]) {
    float score_l[4] = {0.f, 0.f, 0.f, 0.f};
#pragma unroll
    for (int mi = 0; mi < 2; ++mi)
#pragma unroll
        for (int r = 0; r < 4; ++r) {
            float m = fmaxf(fmaxf(acc[mi][0][r], acc[mi][1][r]),
                            fmaxf(acc[mi][2][r], acc[mi][3][r]));
            m = xmax4(m);
            float p[4], s = 0.f;
#pragma unroll
            for (int ni = 0; ni < 4; ++ni) { p[ni] = __expf(acc[mi][ni][r] - m); s += p[ni]; }
            s = xsum4(s);
            float rv = 1.0f / s;
#pragma unroll
            for (int ni = 0; ni < 4; ++ni) score_l[ni] = fmaxf(score_l[ni], p[ni] * rv);
        }
    float tot = 0.f;
#pragma unroll
    for (int ni = 0; ni < 4; ++ni) {
        float v = score_l[ni];
        v = fmaxf(v, __shfl_xor(v, 16));
        v = fmaxf(v, __shfl_xor(v, 32));
        tot += v;
    }
    return xsum4(tot);
}

// ---------------- K1: noisy target scores (wave-per-t; XCD swizzle) ----------
template<bool FAST>
__global__ __launch_bounds__(256, 4) void k_scores(const int* __restrict__ targets,
                                                   const float* __restrict__ emb,
                                                   const _Float16* __restrict__ tab,
                                                   const _Float16* __restrict__ wsA,
                                                   float* __restrict__ wsScr) {
    __shared__ __align__(16) uint4 sA[A_U4];   // 40960 B -> 4 blocks/CU
    int wg = blockIdx.x;
    int xcd = wg & 7, rest = wg >> 3;
    int b = xcd * 8 + (rest >> 6);
    int tg = rest & 63;
    int tid = threadIdx.x;
    {
        const uint4* src = (const uint4*)(wsA + (size_t)b * A_HALF);
        for (int i = tid; i < A_U4; i += 256) sA[i] = src[i];
    }
    __syncthreads();

    int lane = tid & 63, wave = tid >> 6;
    int t = tg * 4 + wave;
    const int* trow = targets + ((size_t)b * T_ + t) * LT;

    f32x4 acc[2][4];
    if (FAST) compute_noisy(sA, tab, trow, lane, acc);
    else      compute_exact<4>(sA, emb, trow, 0, lane, acc);
    float tot = score_from_acc(acc);
    if (lane == 0) wsScr[b * T_ + t] = tot;
}

// ---------------- K2: parallel exact rescore of noisy top-16 ----------------
// Grid (NCAND/4, B_): block (r, b) -> wave w rescores candidate r*4+w.
__global__ __launch_bounds__(256) void k_sel(const int* __restrict__ targets,
                                             const float* __restrict__ emb,
                                             const _Float16* __restrict__ wsA,
                                             const float* __restrict__ wsScr,
                                             int* __restrict__ wsCand,
                                             float* __restrict__ wsScoreC) {
    __shared__ __align__(16) uint4 sA[A_U4];
    __shared__ int sCand[NCAND];
    int r = blockIdx.x, b = blockIdx.y, tid = threadIdx.x;
    int lane = tid & 63, wave = tid >> 6;
    if (wave) {
        const uint4* src = (const uint4*)(wsA + (size_t)b * A_HALF);
        for (int i = tid - 64; i < A_U4; i += 192) sA[i] = src[i];
    } else {
        float v[4];
#pragma unroll
        for (int i = 0; i < 4; ++i) v[i] = wsScr[b * T_ + lane + 64 * i];
        for (int s = 0; s < NCAND; ++s) {
            float bv = v[0]; int bi = lane;
#pragma unroll
            for (int i = 1; i < 4; ++i) {
                int idx = lane + 64 * i;
                if (v[i] > bv) { bv = v[i]; bi = idx; }
            }
            for (int off = 32; off > 0; off >>= 1) {
                float ov = __shfl_down(bv, off);
                int   oi = __shfl_down(bi, off);
                if (ov > bv || (ov == bv && oi < bi)) { bv = ov; bi = oi; }
            }
            bi = __shfl(bi, 0);
            if (lane == 0) {
                sCand[s] = bi;
                if (r == 0) wsCand[b * NCAND + s] = bi;
            }
            if ((bi & 63) == lane) v[bi >> 6] = -1e30f;
        }
    }
    __syncthreads();

    int c = r * 4 + wave;
    int t = sCand[c];
    const int* trow = targets + ((size_t)b * T_ + t) * LT;
    f32x4 acc[2][4];
    compute_exact<4>(sA, emb, trow, 0, lane, acc);
    float tot = score_from_acc(acc);
    if (lane == 0) wsScoreC[b * NCAND + c] = tot;
}

// ---------------- K3: pick rank-j, recompute tile (exact), L2-normalize -----
__global__ __launch_bounds__(256) void k_output(const int* __restrict__ targets,
                                                const float* __restrict__ emb,
                                                const _Float16* __restrict__ wsA,
                                                const int* __restrict__ wsCand,
                                                const float* __restrict__ wsScoreC,
                                                float* __restrict__ out) {
    __shared__ __align__(16) uint4 sA[A_U4];
    __shared__ float sS[LC][4];
    __shared__ int sT;
    int b = blockIdx.y, j = blockIdx.x, tid = threadIdx.x;
    int lane = tid & 63, wave = tid >> 6;
    if (wave) {
        const uint4* src = (const uint4*)(wsA + (size_t)b * A_HALF);
        for (int i = tid - 64; i < A_U4; i += 192) sA[i] = src[i];
    } else if (lane == 0) {
        // exact selection from the 16 (cand, score) pairs — same rules as R9.
        unsigned used = 0; int sel = 0;
        for (int jj = 0; jj <= j; ++jj) {
            float bs = -1e30f; int bt = 0x7fffffff, bsl = 0;
            for (int s = 0; s < NCAND; ++s) {
                if (used & (1u << s)) continue;
                float sc = wsScoreC[b * NCAND + s];
                int tt = wsCand[b * NCAND + s];
                if (sc > bs || (sc == bs && tt < bt)) { bs = sc; bt = tt; bsl = s; }
            }
            used |= (1u << bsl);
            sel = bt;
        }
        sT = sel;
    }
    __syncthreads();

    int t = sT;
    const int* trow = targets + ((size_t)b * T_ + t) * LT;
    f32x4 acc[2][1];
    compute_exact<1>(sA, emb, trow, wave * 16, lane, acc);

    int ln = lane & 15, quad = lane >> 4;
#pragma unroll
    for (int mi = 0; mi < 2; ++mi)
#pragma unroll
        for (int r = 0; r < 4; ++r) {
            float v = acc[mi][0][r] * acc[mi][0][r];
            v = xsum4(v);
            if (ln == 0) sS[mi * 16 + quad * 4 + r][wave] = v;
        }
    __syncthreads();

    float* obase = out + (size_t)(b * NSEL + j) * (LC * LT);
#pragma unroll
    for (int mi = 0; mi < 2; ++mi)
#pragma unroll
        for (int r = 0; r < 4; ++r) {
            int c = mi * 16 + quad * 4 + r;
            float ss = sS[c][0] + sS[c][1] + sS[c][2] + sS[c][3];
            float rinv = 1.0f / sqrtf(ss);
            obase[c * LT + wave * 16 + ln] = acc[mi][0][r] * rinv;
        }
}

extern "C" void kernel_launch(void* const* d_in, const int* in_sizes, int n_in,
                              void* d_out, int out_size, void* d_ws, size_t ws_size,
                              hipStream_t stream) {
    const int*   claim   = (const int*)d_in[0];
    const int*   targets = (const int*)d_in[1];
    const float* emb     = (const float*)d_in[2];
    // d_in[3] is n (=5), compile-time NSEL

    const size_t tabBytes = (size_t)VOCAB * TROW * sizeof(_Float16);   // 32 MB
    const size_t restBytes = (size_t)B_ * A_HALF * sizeof(_Float16)
                           + (size_t)B_ * T_ * sizeof(float)
                           + (size_t)B_ * NCAND * (sizeof(int) + sizeof(float)) + 256;
    bool fast = ws_size >= tabBytes + restBytes;   // deterministic per run

    char* p = (char*)d_ws;
    _Float16* tab = nullptr;
    if (fast) { tab = (_Float16*)p; p += tabBytes; }
    _Float16* wsA = (_Float16*)p; p += (size_t)B_ * A_HALF * sizeof(_Float16);
    float* wsScr = (float*)p;     p += (size_t)B_ * T_ * sizeof(float);
    int*   wsCand = (int*)p;      p += (size_t)B_ * NCAND * sizeof(int);
    float* wsScoreC = (float*)p;
    float* out   = (float*)d_out;

    // 32 rows per block: table needs ceil(50000/32)=1563, claims need 64.
    int tableBlocks = fast ? ((VOCAB + 31) / 32) : 0;
    k_prep<<<dim3(tableBlocks + 64), dim3(256), 0, stream>>>(claim, emb, tab, wsA, tableBlocks);
    if (fast) {
        k_scores<true><<<dim3(B_ * 64), dim3(256), 0, stream>>>(targets, emb, tab, wsA, wsScr);
    } else {
        k_scores<false><<<dim3(B_ * 64), dim3(256), 0, stream>>>(targets, emb, tab, wsA, wsScr);
    }
    k_sel<<<dim3(NCAND / 4, B_), dim3(256), 0, stream>>>(targets, emb, wsA, wsScr, wsCand, wsScoreC);
    k_output<<<dim3(NSEL, B_), dim3(256), 0, stream>>>(targets, emb, wsA, wsCand, wsScoreC, out);
}